// Round 6
// baseline (1378.839 us; speedup 1.0000x reference)
//
#include <hip/hip_runtime.h>

// Octree2Col: masked gather
//   out[n,k,:] = neigh[n,k] >= 0 ? data[neigh[n,k], :] : 0
// N=100000, K=27, C=128, fp32. Floor ~1.45 GB seq @ 6.5 TB/s ~= 222 us.
//
// Round 6: R2 structure (sequential writes, random gathers) + SYSTEM-SCOPE
// stores generated by the COMPILER (__hip_atomic_store relaxed/system ->
// global_store_dwordx2 sc0 sc1). Round 5's hand-rolled `sc0 sc1 nt` inline
// asm produced inf (reserved combo / UB) — never again; let the compiler
// emit the cache policy. Goal: stores write around the cache hierarchy so
// the 51 MB `data` array stays resident and gather reads stop missing.
//   R2 evidence: seq-write + missing reads = 2.7 GB @ 6.8 TB/s (link is
//   fine; caching is the whole game).

typedef float floatx4 __attribute__((ext_vector_type(4)));

__device__ __forceinline__ void store_sys(floatx4 v, floatx4* p) {
    union { floatx4 f; unsigned long long u[2]; } c;
    c.f = v;
    unsigned long long* q = (unsigned long long*)p;
    // relaxed system-scope: sc0 sc1 store, no fences
    __hip_atomic_store(&q[0], c.u[0], __ATOMIC_RELAXED, __HIP_MEMORY_SCOPE_SYSTEM);
    __hip_atomic_store(&q[1], c.u[1], __ATOMIC_RELAXED, __HIP_MEMORY_SCOPE_SYSTEM);
}

__global__ __launch_bounds__(256) void octree2col_sysstore(
    const floatx4* __restrict__ data,   // [N, 32]  (N x C as float4)
    const int*     __restrict__ neigh,  // [N*K]
    floatx4*       __restrict__ out,    // [N*K, 32]
    int total_f4)                       // N*K*(C/4)
{
    const int step = gridDim.x * blockDim.x;
    int g = blockIdx.x * blockDim.x + threadIdx.x;

    // 4 independent elements per iteration (MLP)
    for (; g + 3 * step < total_f4; g += 4 * step) {
        const int g0 = g, g1 = g + step, g2 = g + 2 * step, g3 = g + 3 * step;

        const int i0 = neigh[g0 >> 5];          // 32 lanes broadcast one row
        const int i1 = neigh[g1 >> 5];
        const int i2 = neigh[g2 >> 5];
        const int i3 = neigh[g3 >> 5];

        floatx4 v0 = {0.f, 0.f, 0.f, 0.f};
        floatx4 v1 = v0, v2 = v0, v3 = v0;

        // gathers: 512B-contiguous per row; want these cache-resident
        if (i0 >= 0) v0 = data[i0 * 32 + (g0 & 31)];
        if (i1 >= 0) v1 = data[i1 * 32 + (g1 & 31)];
        if (i2 >= 0) v2 = data[i2 * 32 + (g2 & 31)];
        if (i3 >= 0) v3 = data[i3 * 32 + (g3 & 31)];

        // fully sequential, system-scope (write-around) stream writes
        store_sys(v0, &out[g0]);
        store_sys(v1, &out[g1]);
        store_sys(v2, &out[g2]);
        store_sys(v3, &out[g3]);
    }

    for (; g < total_f4; g += step) {
        const int idx = neigh[g >> 5];
        floatx4 v = {0.f, 0.f, 0.f, 0.f};
        if (idx >= 0) v = data[idx * 32 + (g & 31)];
        store_sys(v, &out[g]);
    }
}

extern "C" void kernel_launch(void* const* d_in, const int* in_sizes, int n_in,
                              void* d_out, int out_size, void* d_ws, size_t ws_size,
                              hipStream_t stream) {
    const floatx4* data  = (const floatx4*)d_in[0];
    const int*     neigh = (const int*)d_in[1];
    floatx4*       out   = (floatx4*)d_out;

    int total_f4 = out_size / 4;               // N*K*C / 4
    const int threads = 256;
    int blocks = (total_f4 + threads - 1) / threads;
    if (blocks > 2048) blocks = 2048;          // 8 wg/CU, all co-resident

    octree2col_sysstore<<<blocks, threads, 0, stream>>>(data, neigh, out, total_f4);
}

// Round 7
// 338.848 us; speedup vs baseline: 4.0692x; 4.0692x over previous
//
#include <hip/hip_runtime.h>
#include <climits>

// Octree2Col: masked gather
//   out[n,k,:] = neigh[n,k] >= 0 ? data[neigh[n,k], :] : 0
// N=100000, K=27, C=128, fp32.
//
// Round 7: polished R4 (bin-by-chunk, XCD-owned chunks).
//   Measured map of the design space:
//     R2 seq-writes + uncached reads : 2.7 GB @ 6.8 TB/s = 396 us
//     R4 chunked reads + 512B scatter: 1.45GB @ 4.75TB/s = 327 us  <- best
//     R6 system-scope stores         : 2x write amplification, 1378 us (dead end)
//   Binding constraint: scattered 512 B row writes run ~72% of peak; no gfx950
//   store policy fixes that without breaking something else. So: minimize all
//   other traffic + maximize MLP in the copy kernel.
//   Changes vs R4: pairs packed to 4 B (row<<10 | idx_off, 0.5 MB chunks,
//   NB=98), k_copy unrolled x4 (4 independent entries in flight per half-wave).

typedef float floatx4 __attribute__((ext_vector_type(4)));

constexpr int CH_LOG     = 10;    // 1024 data rows / bucket = 0.5 MB chunk
constexpr int CH_MASK    = (1 << CH_LOG) - 1;
constexpr int K1_THREADS = 1024;
constexpr int K2_BLOCKS  = 2048;  // 8/CU; bid&7 = XCD, bid>>3 = 0..255 local
constexpr int K2_THREADS = 256;

__global__ void k_zero(int* __restrict__ cursor, int NB) {
    if ((int)threadIdx.x < NB) cursor[threadIdx.x] = 0;
}

// -------- K1: bin output rows by data-row chunk; zero-fill invalid ---------
__global__ __launch_bounds__(K1_THREADS) void k_bin(
    const int* __restrict__ neigh,     // [R]
    const floatx4* __restrict__ data,
    floatx4*   __restrict__ out,
    unsigned*  __restrict__ pairs,     // [NB*cap] packed (row<<CH_LOG | off)
    int*       __restrict__ cursor,    // [NB], zeroed
    int R, int NB, int cap)
{
    extern __shared__ int lds[];       // l_cnt[NB], l_base[NB]
    int* l_cnt  = lds;
    int* l_base = lds + NB;
    for (int i = threadIdx.x; i < NB; i += K1_THREADS) l_cnt[i] = 0;
    __syncthreads();

    const int r = blockIdx.x * K1_THREADS + threadIdx.x;
    int idx = INT_MIN, b = 0, rank = 0;
    if (r < R) {
        idx = neigh[r];
        if (idx >= 0) {
            b = idx >> CH_LOG;
            rank = atomicAdd(&l_cnt[b], 1);       // intra-block rank
        }
    }
    __syncthreads();
    for (int i = threadIdx.x; i < NB; i += K1_THREADS)
        l_base[i] = atomicAdd(&cursor[i], l_cnt[i]);  // reserve block's range
    __syncthreads();

    if (idx >= 0) {
        const int slot = l_base[b] + rank;
        if (slot < cap) {
            // cached 4B store; pairs region is small, L2 write-combines it
            pairs[(size_t)b * cap + slot] =
                ((unsigned)r << CH_LOG) | (unsigned)(idx & CH_MASK);
        } else {
            // statistical overflow safety net (cap = mean+25%: ~never)
            const floatx4* s = data + (size_t)idx * 32;
            floatx4*       d = out  + (size_t)r   * 32;
            for (int c = 0; c < 32; ++c) __builtin_nontemporal_store(s[c], &d[c]);
        }
    } else if (idx == -1) {
        const floatx4 z = {0.f, 0.f, 0.f, 0.f};
        floatx4* d = out + (size_t)r * 32;
        for (int c = 0; c < 32; ++c) __builtin_nontemporal_store(z, &d[c]);
    }
}

// -------- K2: per-XCD chunk ownership; half-wave copies one 512 B row ------
__device__ __forceinline__ void copy_row(
    const floatx4* __restrict__ data, floatx4* __restrict__ out,
    size_t chunk_row0, unsigned p, int c4)
{
    const floatx4 v = data[(chunk_row0 + (p & CH_MASK)) * 32 + c4];
    __builtin_nontemporal_store(v, &out[(size_t)(p >> CH_LOG) * 32 + c4]);
}

__global__ __launch_bounds__(K2_THREADS) void k_copy(
    const floatx4*  __restrict__ data,
    floatx4*        __restrict__ out,
    const unsigned* __restrict__ pairs,
    const int*      __restrict__ cursor,
    int NB, int cap)
{
    const int hw   = threadIdx.x >> 5;   // half-wave 0..7
    const int c4   = threadIdx.x & 31;   // float4 col in 512 B row
    const int xcd  = blockIdx.x & 7;     // MI355X round-robin XCD mapping
    const int lblk = blockIdx.x >> 3;    // 0..255 within XCD

    const int NB_full = NB & ~7;

    for (int b = xcd; b < NB_full; b += 8) {       // chunks owned by this XCD
        int cnt = cursor[b]; if (cnt > cap) cnt = cap;
        const int lo = (int)(((long long)cnt * lblk)       >> 8);
        const int hi = (int)(((long long)cnt * (lblk + 1)) >> 8);
        const unsigned* pb = pairs + (size_t)b * cap;
        const size_t chunk_row0 = (size_t)b << CH_LOG;

        int e = lo + hw;
        for (; e + 24 < hi; e += 32) {             // x4 MLP
            const unsigned p0 = pb[e];
            const unsigned p1 = pb[e + 8];
            const unsigned p2 = pb[e + 16];
            const unsigned p3 = pb[e + 24];
            copy_row(data, out, chunk_row0, p0, c4);
            copy_row(data, out, chunk_row0, p1, c4);
            copy_row(data, out, chunk_row0, p2, c4);
            copy_row(data, out, chunk_row0, p3, c4);
        }
        for (; e < hi; e += 8)
            copy_row(data, out, chunk_row0, pb[e], c4);
    }

    // leftover buckets (NB % 8): split across ALL blocks
    for (int b = NB_full; b < NB; ++b) {
        int cnt = cursor[b]; if (cnt > cap) cnt = cap;
        const int lo = (int)((long long)cnt * blockIdx.x       / K2_BLOCKS);
        const int hi = (int)((long long)cnt * (blockIdx.x + 1) / K2_BLOCKS);
        const unsigned* pb = pairs + (size_t)b * cap;
        const size_t chunk_row0 = (size_t)b << CH_LOG;
        for (int e = lo + hw; e < hi; e += 8)
            copy_row(data, out, chunk_row0, pb[e], c4);
    }
}

// ---------------- fallback (round-3 chunked kernel, 330 us) ----------------
constexpr int ROWS_PER_CHUNK = 8192;
constexpr int FB_THREADS = 256;
constexpr int FB_BLOCKS  = 2048;
constexpr int FB_WAVES   = FB_BLOCKS * FB_THREADS / 64;
constexpr int GPW        = 6;

__global__ __launch_bounds__(FB_THREADS) void octree2col_chunked(
    const floatx4* __restrict__ data, const int* __restrict__ neigh,
    floatx4* __restrict__ out, int rows_total, int n_data_rows)
{
    const int wave = (blockIdx.x * FB_THREADS + threadIdx.x) >> 6;
    const int lane = threadIdx.x & 63;
    const int half = lane >> 5;
    const int c4   = lane & 31;
    const int ngroups = (rows_total + 63) >> 6;
    const int nchunks = (n_data_rows + ROWS_PER_CHUNK - 1) / ROWS_PER_CHUNK;

    int nv[GPW]; int gbase[GPW];
#pragma unroll
    for (int i = 0; i < GPW; ++i) {
        const int g = wave + i * FB_WAVES;
        gbase[i] = g << 6;
        const int row = gbase[i] + lane;
        nv[i] = (g < ngroups && row < rows_total) ? neigh[row] : INT_MIN;
    }
#pragma unroll
    for (int i = 0; i < GPW; ++i) {
        unsigned long long zm = __ballot(nv[i] == -1);
        while (zm) {
            int r1 = __builtin_ctzll(zm); zm &= zm - 1;
            int r2 = -1;
            if (zm) { r2 = __builtin_ctzll(zm); zm &= zm - 1; }
            const int r = half ? r2 : r1;
            if (r >= 0) {
                const long long row = gbase[i] + r;
                floatx4 z = {0.f, 0.f, 0.f, 0.f};
                __builtin_nontemporal_store(z, &out[row * 32 + c4]);
            }
        }
    }
    for (int p = 0; p < nchunks; ++p) {
        const int lo = p * ROWS_PER_CHUNK;
#pragma unroll
        for (int i = 0; i < GPW; ++i) {
            unsigned long long m =
                __ballot((unsigned)(nv[i] - lo) < (unsigned)ROWS_PER_CHUNK);
            while (m) {
                int r1 = __builtin_ctzll(m); m &= m - 1;
                int r2 = -1;
                if (m) { r2 = __builtin_ctzll(m); m &= m - 1; }
                const int r  = half ? r2 : r1;
                const int rs = r < 0 ? 0 : r;
                const int idx = __shfl(nv[i], rs);
                if (r >= 0) {
                    const long long row = gbase[i] + r;
                    floatx4 v = data[(long long)idx * 32 + c4];
                    __builtin_nontemporal_store(v, &out[row * 32 + c4]);
                }
            }
        }
        __syncthreads();
    }
}

// ---------------------------------------------------------------------------
extern "C" void kernel_launch(void* const* d_in, const int* in_sizes, int n_in,
                              void* d_out, int out_size, void* d_ws, size_t ws_size,
                              hipStream_t stream) {
    const floatx4* data  = (const floatx4*)d_in[0];
    const int*     neigh = (const int*)d_in[1];
    floatx4*       out   = (floatx4*)d_out;

    const int R = in_sizes[1];          // N*K output rows
    const int N = in_sizes[0] / 128;    // data rows (C=128)
    const int NB = (N + (1 << CH_LOG) - 1) >> CH_LOG;   // 98 buckets

    // expected entries per full bucket = R*2^CH_LOG/N; cap = 1.25x, 64-aligned
    long long mean = (((long long)R << CH_LOG) + N - 1) / N;
    int cap = (int)((mean * 5 + 3) / 4);
    cap = (cap + 63) & ~63;
    const size_t need = 1024 + (size_t)NB * (size_t)cap * sizeof(unsigned);
    const bool row_fits = (long long)R < (1LL << (32 - CH_LOG));

    if (ws_size >= need && NB <= 1024 && row_fits) {
        int*      cursor = (int*)d_ws;
        unsigned* pairs  = (unsigned*)((char*)d_ws + 1024);

        k_zero<<<1, 1024, 0, stream>>>(cursor, NB);

        const int k1_blocks = (R + K1_THREADS - 1) / K1_THREADS;
        const size_t lds = 2 * (size_t)NB * sizeof(int);
        k_bin<<<k1_blocks, K1_THREADS, lds, stream>>>(
            neigh, data, out, pairs, cursor, R, NB, cap);

        k_copy<<<K2_BLOCKS, K2_THREADS, 0, stream>>>(
            data, out, pairs, cursor, NB, cap);
    } else {
        octree2col_chunked<<<FB_BLOCKS, FB_THREADS, 0, stream>>>(
            data, neigh, out, R, N);
    }
}

// Round 8
// 329.182 us; speedup vs baseline: 4.1887x; 1.0294x over previous
//
#include <hip/hip_runtime.h>
#include <climits>

// Octree2Col: masked gather
//   out[n,k,:] = neigh[n,k] >= 0 ? data[neigh[n,k], :] : 0
// N=100000, K=27, C=128, fp32.
//
// FINAL (= Round-4 build, measured 327.7 us; R7's micro-tuning regressed to
// 338.8 and is reverted).
//
// Design-space map (all measured):
//   R2 seq writes + uncached random reads : 2.7 GB @ 6.8 TB/s = 396 us
//   R3 chunk passes, all XCDs             : 330 us
//   R4 bin-by-chunk, XCD-owned chunks     : 327.7 us   <-- this kernel
//   R6 system-scope (write-around) stores : 2x write amplification, 1378 us
//   R7 packed pairs + x4 unroll           : 338.8 us (regression)
// Binding constraint: scattered 512 B row writes run ~4.7 TB/s (~72% of the
// 6.5 TB/s sequential ceiling); reads are L2-chunk-resident and nearly free.
// Floor model: 1.43 GB @ 4.7 TB/s (~300 us k_copy) + ~25 us binning = ~325 us.

typedef float floatx4 __attribute__((ext_vector_type(4)));

constexpr int CH_LOG     = 11;    // 2048 data rows per bucket = 1 MB chunk
constexpr int K1_THREADS = 1024;
constexpr int K2_BLOCKS  = 2048;  // 8 per CU; bid&7 = XCD, bid>>3 = 0..255 local
constexpr int K2_THREADS = 256;

// -------- tiny init: zero bucket cursors ----------------------------------
__global__ void k_zero(int* __restrict__ cursor, int NB) {
    if ((int)threadIdx.x < NB) cursor[threadIdx.x] = 0;
}

// -------- K1: bin output rows by data-row bucket; zero-fill invalid --------
__global__ __launch_bounds__(K1_THREADS) void k_bin(
    const int* __restrict__ neigh,   // [R]
    const floatx4* __restrict__ data,
    floatx4*   __restrict__ out,
    int2*      __restrict__ pairs,   // [NB * cap] (row, idx)
    int*       __restrict__ cursor,  // [NB], zeroed
    int R, int NB, int cap)
{
    extern __shared__ int lds[];     // l_cnt[NB], l_base[NB]
    int* l_cnt  = lds;
    int* l_base = lds + NB;
    for (int i = threadIdx.x; i < NB; i += K1_THREADS) l_cnt[i] = 0;
    __syncthreads();

    const int r = blockIdx.x * K1_THREADS + threadIdx.x;
    int idx = INT_MIN, b = 0, rank = 0;
    if (r < R) {
        idx = neigh[r];
        if (idx >= 0) {
            b = idx >> CH_LOG;
            rank = atomicAdd(&l_cnt[b], 1);     // intra-block rank in bucket
        }
    }
    __syncthreads();
    for (int i = threadIdx.x; i < NB; i += K1_THREADS)
        l_base[i] = atomicAdd(&cursor[i], l_cnt[i]);  // reserve block's range
    __syncthreads();

    if (idx >= 0) {
        const int slot = l_base[b] + rank;
        if (slot < cap) {
            pairs[(size_t)b * cap + slot] = make_int2(r, idx);
        } else {
            // statistical overflow safety net (cap = mean+25%: ~never taken)
            const floatx4* s = data + (size_t)idx * 32;
            floatx4*       d = out  + (size_t)r   * 32;
            for (int c = 0; c < 32; ++c) __builtin_nontemporal_store(s[c], &d[c]);
        }
    } else if (idx == -1) {
        // invalid neighbor: zero-fill (uniform randint(-1,N): ~R/N rows total)
        const floatx4 z = {0.f, 0.f, 0.f, 0.f};
        floatx4* d = out + (size_t)r * 32;
        for (int c = 0; c < 32; ++c) __builtin_nontemporal_store(z, &d[c]);
    }
}

// -------- K2: per-XCD chunk ownership; half-wave copies one 512 B row ------
__global__ __launch_bounds__(K2_THREADS) void k_copy(
    const floatx4* __restrict__ data,
    floatx4*       __restrict__ out,
    const int2*    __restrict__ pairs,
    const int*     __restrict__ cursor,
    int NB, int cap)
{
    const int hw   = threadIdx.x >> 5;   // half-wave id 0..7
    const int c4   = threadIdx.x & 31;   // float4 column in 512 B row
    const int xcd  = blockIdx.x & 7;     // MI355X round-robin XCD mapping
    const int lblk = blockIdx.x >> 3;    // 0..255 within this XCD

    const int NB_full = NB & ~7;

    // buckets owned by this XCD: chunk lives in exactly one L2
    for (int b = xcd; b < NB_full; b += 8) {
        int cnt = cursor[b]; if (cnt > cap) cnt = cap;
        const int lo = (int)(((long long)cnt * lblk)       >> 8);
        const int hi = (int)(((long long)cnt * (lblk + 1)) >> 8);
        const int2* pb = pairs + (size_t)b * cap;
        for (int e = lo + hw; e < hi; e += 8) {
            const int2 pr = pb[e];                              // broadcast 8B
            const floatx4 v = data[(size_t)pr.y * 32 + c4];     // L2-hot chunk
            __builtin_nontemporal_store(v, &out[(size_t)pr.x * 32 + c4]);
        }
    }
    // leftover buckets (NB % 8): split across ALL blocks for load balance
    for (int b = NB_full; b < NB; ++b) {
        int cnt = cursor[b]; if (cnt > cap) cnt = cap;
        const int lo = (int)((long long)cnt * blockIdx.x       / K2_BLOCKS);
        const int hi = (int)((long long)cnt * (blockIdx.x + 1) / K2_BLOCKS);
        const int2* pb = pairs + (size_t)b * cap;
        for (int e = lo + hw; e < hi; e += 8) {
            const int2 pr = pb[e];
            const floatx4 v = data[(size_t)pr.y * 32 + c4];
            __builtin_nontemporal_store(v, &out[(size_t)pr.x * 32 + c4]);
        }
    }
}

// ---------------- fallback (round-3 chunked kernel, 330 us) ----------------
constexpr int ROWS_PER_CHUNK = 8192;
constexpr int FB_THREADS = 256;
constexpr int FB_BLOCKS  = 2048;
constexpr int FB_WAVES   = FB_BLOCKS * FB_THREADS / 64;
constexpr int GPW        = 6;

__global__ __launch_bounds__(FB_THREADS) void octree2col_chunked(
    const floatx4* __restrict__ data, const int* __restrict__ neigh,
    floatx4* __restrict__ out, int rows_total, int n_data_rows)
{
    const int wave = (blockIdx.x * FB_THREADS + threadIdx.x) >> 6;
    const int lane = threadIdx.x & 63;
    const int half = lane >> 5;
    const int c4   = lane & 31;
    const int ngroups = (rows_total + 63) >> 6;
    const int nchunks = (n_data_rows + ROWS_PER_CHUNK - 1) / ROWS_PER_CHUNK;

    int nv[GPW]; int gbase[GPW];
#pragma unroll
    for (int i = 0; i < GPW; ++i) {
        const int g = wave + i * FB_WAVES;
        gbase[i] = g << 6;
        const int row = gbase[i] + lane;
        nv[i] = (g < ngroups && row < rows_total) ? neigh[row] : INT_MIN;
    }
#pragma unroll
    for (int i = 0; i < GPW; ++i) {
        unsigned long long zm = __ballot(nv[i] == -1);
        while (zm) {
            int r1 = __builtin_ctzll(zm); zm &= zm - 1;
            int r2 = -1;
            if (zm) { r2 = __builtin_ctzll(zm); zm &= zm - 1; }
            const int r = half ? r2 : r1;
            if (r >= 0) {
                const long long row = gbase[i] + r;
                floatx4 z = {0.f, 0.f, 0.f, 0.f};
                __builtin_nontemporal_store(z, &out[row * 32 + c4]);
            }
        }
    }
    for (int p = 0; p < nchunks; ++p) {
        const int lo = p * ROWS_PER_CHUNK;
#pragma unroll
        for (int i = 0; i < GPW; ++i) {
            unsigned long long m =
                __ballot((unsigned)(nv[i] - lo) < (unsigned)ROWS_PER_CHUNK);
            while (m) {
                int r1 = __builtin_ctzll(m); m &= m - 1;
                int r2 = -1;
                if (m) { r2 = __builtin_ctzll(m); m &= m - 1; }
                const int r  = half ? r2 : r1;
                const int rs = r < 0 ? 0 : r;
                const int idx = __shfl(nv[i], rs);
                if (r >= 0) {
                    const long long row = gbase[i] + r;
                    floatx4 v = data[(long long)idx * 32 + c4];
                    __builtin_nontemporal_store(v, &out[row * 32 + c4]);
                }
            }
        }
        __syncthreads();
    }
}

// ---------------------------------------------------------------------------
extern "C" void kernel_launch(void* const* d_in, const int* in_sizes, int n_in,
                              void* d_out, int out_size, void* d_ws, size_t ws_size,
                              hipStream_t stream) {
    const floatx4* data  = (const floatx4*)d_in[0];
    const int*     neigh = (const int*)d_in[1];
    floatx4*       out   = (floatx4*)d_out;

    const int R = in_sizes[1];          // N*K output rows
    const int N = in_sizes[0] / 128;    // data rows (C=128)
    const int NB = (N + (1 << CH_LOG) - 1) >> CH_LOG;   // 49 buckets

    // per-full-bucket expected entries = R * 2048 / N; cap = 1.25x, 64-aligned
    long long mean = (((long long)R << CH_LOG) + N - 1) / N;
    int cap = (int)((mean * 5 + 3) / 4);
    cap = (cap + 63) & ~63;
    const size_t need = 1024 + (size_t)NB * (size_t)cap * sizeof(int2);

    if (ws_size >= need && NB <= 1024) {
        int*  cursor = (int*)d_ws;
        int2* pairs  = (int2*)((char*)d_ws + 1024);

        k_zero<<<1, 1024, 0, stream>>>(cursor, NB);

        const int k1_blocks = (R + K1_THREADS - 1) / K1_THREADS;
        const size_t lds = 2 * (size_t)NB * sizeof(int);
        k_bin<<<k1_blocks, K1_THREADS, lds, stream>>>(
            neigh, data, out, pairs, cursor, R, NB, cap);

        k_copy<<<K2_BLOCKS, K2_THREADS, 0, stream>>>(
            data, out, pairs, cursor, NB, cap);
    } else {
        octree2col_chunked<<<FB_BLOCKS, FB_THREADS, 0, stream>>>(
            data, neigh, out, R, N);
    }
}